// Round 6
// baseline (205.804 us; speedup 1.0000x reference)
//
#include <hip/hip_runtime.h>

#define EPS_BN 1e-5f

// Problem constants: B=8, CH=64, H=W=64  (all I/O float32)
constexpr int Bn   = 8;
constexpr int CHn  = 64;
constexpr int HWn  = 4096;   // 64*64
constexpr int HW4n = 1024;   // pooled
constexpr int CQn  = 8;      // CH/8
constexpr int CVn  = 32;     // CH/2

// Module-scope scratch; fully rewritten every call.
// g_K: [b][m][8]              (256 KiB)
// g_V: [b][q4(8)][row(1024)][4]  (1 MiB)  -- channel-group-major for staged loads
__device__ __align__(16) float g_K[Bn * HW4n * CQn];
__device__ __align__(16) float g_V[Bn * HW4n * CVn];

// ------------- Kernel A: K,V projection + BN + 2x2 maxpool -------------------
// 256 blocks x 192 threads. Block = one pooled row (32 pooled px) of one batch.
__global__ __launch_bounds__(192)
void k_proj_kv(const float* __restrict__ mem,
               const float* __restrict__ wk,  const float* __restrict__ bk,
               const float* __restrict__ ks,  const float* __restrict__ kb,
               const float* __restrict__ km,  const float* __restrict__ kv,
               const float* __restrict__ wv,  const float* __restrict__ bv_,
               const float* __restrict__ vs,  const float* __restrict__ vb,
               const float* __restrict__ vm,  const float* __restrict__ vv)
{
    __shared__ float wall[2560];   // [ch][40]: c 0..7 = K, 8..39 = V (BN folded)
    __shared__ float beta[40];
    __shared__ float Msh[8192];    // [ch][32 quads][4 px], 32 KB

    const int tid = threadIdx.x;
    for (int idx = tid; idx < 2560; idx += 192) {
        int c = idx % 40, ch = idx / 40;
        float w, inv;
        if (c < 8) { inv = ks[c] * rsqrtf(kv[c] + EPS_BN); w = wk[c * 64 + ch]; }
        else { int c2 = c - 8; inv = vs[c2] * rsqrtf(vv[c2] + EPS_BN); w = wv[c2 * 64 + ch]; }
        wall[ch * 40 + c] = w * inv;
    }
    if (tid < 40) {
        int c = tid;
        if (c < 8) {
            float inv = ks[c] * rsqrtf(kv[c] + EPS_BN);
            beta[c] = (bk[c] - km[c]) * inv + kb[c];
        } else {
            int c2 = c - 8;
            float inv = vs[c2] * rsqrtf(vv[c2] + EPS_BN);
            beta[c] = (bv_[c2] - vm[c2]) * inv + vb[c2];
        }
    }

    const int b = blockIdx.x >> 5;        // 32 blocks per batch
    const int R = blockIdx.x & 31;        // pooled row

    // ---- stage source tile: rows 2R,2R+1, all 64 cols, all 64 ch ----
    {
        const float* src = mem + (size_t)b * (CHn * HWn) + (R << 7);
        for (int idx = tid; idx < 4096; idx += 192) {
            int ch = idx >> 6, p2 = idx & 63;
            float2 v = *(const float2*)(src + ch * HWn + (p2 << 1));
            int r = p2 >> 5, w2 = p2 & 31;
            *(float2*)&Msh[ch * 128 + (w2 << 2) + (r << 1)] = v;
        }
    }
    __syncthreads();

    if (tid < 160) {
        const int g  = tid % 5;        // out group: 0 = K(8ch), 1..4 = V 8ch each
        const int qd = tid / 5;        // pooled col 0..31
        float acc[4][8];
        #pragma unroll
        for (int p = 0; p < 4; ++p)
            #pragma unroll
            for (int c = 0; c < 8; ++c) acc[p][c] = 0.f;

        for (int ch = 0; ch < 64; ++ch) {
            const float4 mq = *(const float4*)&Msh[ch * 128 + (qd << 2)];
            const float4* wr = (const float4*)&wall[ch * 40 + (g << 3)];
            const float4 w0 = wr[0], w1 = wr[1];
            #pragma unroll
            for (int p = 0; p < 4; ++p) {
                const float mv = (p == 0) ? mq.x : (p == 1) ? mq.y : (p == 2) ? mq.z : mq.w;
                acc[p][0] = fmaf(w0.x, mv, acc[p][0]); acc[p][1] = fmaf(w0.y, mv, acc[p][1]);
                acc[p][2] = fmaf(w0.z, mv, acc[p][2]); acc[p][3] = fmaf(w0.w, mv, acc[p][3]);
                acc[p][4] = fmaf(w1.x, mv, acc[p][4]); acc[p][5] = fmaf(w1.y, mv, acc[p][5]);
                acc[p][6] = fmaf(w1.z, mv, acc[p][6]); acc[p][7] = fmaf(w1.w, mv, acc[p][7]);
            }
        }
        float o[8];
        #pragma unroll
        for (int c = 0; c < 8; ++c)
            o[c] = fmaxf(fmaxf(acc[0][c], acc[1][c]), fmaxf(acc[2][c], acc[3][c]))
                 + beta[(g << 3) + c];

        const int m = (R << 5) + qd;
        if (g == 0) {
            float4* kp = (float4*)(g_K + ((size_t)b * HW4n + m) * CQn);
            kp[0] = make_float4(o[0], o[1], o[2], o[3]);
            kp[1] = make_float4(o[4], o[5], o[6], o[7]);
        } else {
            // g_V layout [b][q4][row][4]; this group covers q4 = 2(g-1), 2(g-1)+1
            float4* vp = (float4*)(g_V + (size_t)b * (HW4n * CVn)
                                       + (size_t)((g - 1) << 1) * (HW4n * 4)) + m;
            vp[0]     = make_float4(o[0], o[1], o[2], o[3]);
            vp[1024]  = make_float4(o[4], o[5], o[6], o[7]);
        }
    }
}

// ------ Kernel B: fused Q-proj + online-softmax attention + out-proj ---------
// 512 blocks x 256 threads, 2 blocks/CU. 16-lane group owns 4 queries; lane j
// handles keys ≡ j (mod 16). Single pass (online softmax), scores in regs.
__global__ __launch_bounds__(256, 2)
void k_attn3(const float* __restrict__ mem,
             const float* __restrict__ x,
             const float* __restrict__ wq, const float* __restrict__ bq,
             const float* __restrict__ qs, const float* __restrict__ qb,
             const float* __restrict__ qm, const float* __restrict__ qv,
             const float* __restrict__ wp, const float* __restrict__ bp,
             const float* __restrict__ ps, const float* __restrict__ pb,
             const float* __restrict__ pm, const float* __restrict__ pv,
             const float* __restrict__ gamma,
             float* __restrict__ out)
{
    __shared__ float qw[512];      // folded Q weights [ch][8]
    __shared__ float qbeta[8];
    __shared__ float wpf[2048];    // folded out-proj weights [o][32]
    __shared__ float pbeta[64];
    __shared__ float Ksh[8192];    // K[1024][8], XOR-swizzled float4 slots, 32 KB
    __shared__ float Vsh[4608];    // V chunk: 128 rows x 36-pitch, 18 KB

    const int tid  = threadIdx.x;
    const int j    = tid & 15;           // key-split lane within 16-lane group
    const int grp  = tid >> 4;           // 0..15, 4 queries each
    const int b    = blockIdx.x >> 6;    // 64 tiles per batch
    const int tile = blockIdx.x & 63;
    const int n0   = (tile << 6) + (grp << 2);   // group's first query
    const int bx   = (j >> 2) & 3;               // per-lane K slot XOR

    // ---- stage folded weights ----
    const float gm = gamma[0];
    for (int idx = tid; idx < 512; idx += 256) {
        int c = idx & 7, ch = idx >> 3;
        float inv = qs[c] * rsqrtf(qv[c] + EPS_BN);
        qw[idx] = wq[c * 64 + ch] * inv;
    }
    if (tid < 8) {
        float inv = qs[tid] * rsqrtf(qv[tid] + EPS_BN);
        qbeta[tid] = (bq[tid] - qm[tid]) * inv + qb[tid];
    }
    for (int idx = tid; idx < 2048; idx += 256) {
        int o = idx >> 5, cc = idx & 31;
        float inv = ps[o] * rsqrtf(pv[o] + EPS_BN);
        wpf[idx] = wp[o * 32 + cc] * inv * gm;
    }
    if (tid < 64) {
        float inv = ps[tid] * rsqrtf(pv[tid] + EPS_BN);
        pbeta[tid] = gm * ((bp[tid] - pm[tid]) * inv + pb[tid]);
    }
    // ---- stage K (this batch), XOR-swizzled: slot = idx4 ^ ((idx4>>3)&3) ----
    {
        const float4* Ks4 = (const float4*)(g_K + (size_t)b * (HW4n * CQn));
        float4* Kd4 = (float4*)Ksh;
        #pragma unroll
        for (int i = 0; i < 8; ++i) {
            int idx = (i << 8) | tid;
            Kd4[idx ^ ((idx >> 3) & 3)] = Ks4[idx];
        }
    }
    __syncthreads();

    // ---- Q projection: lane j handles ch ≡ j (mod 16), 4 queries ----
    float qreg[4][8];
    #pragma unroll
    for (int qq = 0; qq < 4; ++qq)
        #pragma unroll
        for (int c = 0; c < 8; ++c) qreg[qq][c] = 0.f;
    {
        const float* mp = mem + (size_t)b * (CHn * HWn) + n0;
        #pragma unroll
        for (int cc = 0; cc < 4; ++cc) {
            int ch = (cc << 4) | j;
            float4 mv4 = *(const float4*)(mp + ch * HWn);   // 4 queries
            const float4* wr = (const float4*)&qw[ch * 8];
            float4 w0 = wr[0], w1 = wr[1];
            #pragma unroll
            for (int qq = 0; qq < 4; ++qq) {
                const float mv = (qq == 0) ? mv4.x : (qq == 1) ? mv4.y : (qq == 2) ? mv4.z : mv4.w;
                qreg[qq][0] = fmaf(w0.x, mv, qreg[qq][0]); qreg[qq][1] = fmaf(w0.y, mv, qreg[qq][1]);
                qreg[qq][2] = fmaf(w0.z, mv, qreg[qq][2]); qreg[qq][3] = fmaf(w0.w, mv, qreg[qq][3]);
                qreg[qq][4] = fmaf(w1.x, mv, qreg[qq][4]); qreg[qq][5] = fmaf(w1.y, mv, qreg[qq][5]);
                qreg[qq][6] = fmaf(w1.z, mv, qreg[qq][6]); qreg[qq][7] = fmaf(w1.w, mv, qreg[qq][7]);
            }
        }
        #pragma unroll
        for (int qq = 0; qq < 4; ++qq)
            #pragma unroll
            for (int c = 0; c < 8; ++c) {
                float v = qreg[qq][c];
                v += __shfl_xor(v, 1); v += __shfl_xor(v, 2);
                v += __shfl_xor(v, 4); v += __shfl_xor(v, 8);
                qreg[qq][c] = v + qbeta[c];
            }
    }

    const float4* K4 = (const float4*)Ksh;

    // ---- online softmax state ----
    float m_[4], l_[4], acc[4][32];
    #pragma unroll
    for (int qq = 0; qq < 4; ++qq) {
        m_[qq] = -3.0e38f; l_[qq] = 0.f;
        #pragma unroll
        for (int c = 0; c < 32; ++c) acc[qq][c] = 0.f;
    }

    const float4* Vglob = (const float4*)(g_V + (size_t)b * (HW4n * CVn));

    for (int c = 0; c < 8; ++c) {
        __syncthreads();   // previous chunk fully consumed
        // stage V chunk: global [q4][row] -> LDS row*9+q4 (float4 slots)
        {
            float4* Vd4 = (float4*)Vsh;
            #pragma unroll
            for (int i = 0; i < 4; ++i) {
                int idx = (i << 8) | tid;
                int q4 = idx >> 7, row = idx & 127;
                Vd4[row * 9 + q4] = Vglob[(q4 << 10) + (c << 7) + row];
            }
        }
        __syncthreads();

        // ---- score phase: 8 keys/lane, 4 queries ----
        float s[4][8];
        #pragma unroll
        for (int mm = 0; mm < 8; ++mm) {
            const int m  = (c << 7) | (mm << 4) | j;
            const int b4 = 2 * m;
            const float4 k0 = K4[b4 ^ bx], k1 = K4[(b4 + 1) ^ bx];
            #pragma unroll
            for (int qq = 0; qq < 4; ++qq) {
                const float* q = qreg[qq];
                s[qq][mm] = fmaf(q[0], k0.x, fmaf(q[1], k0.y, fmaf(q[2], k0.z, fmaf(q[3], k0.w,
                            fmaf(q[4], k1.x, fmaf(q[5], k1.y, fmaf(q[6], k1.z, q[7] * k1.w)))))));
            }
        }
        // ---- online update + exp (scores -> weights in place) ----
        #pragma unroll
        for (int qq = 0; qq < 4; ++qq) {
            float cm = s[qq][0];
            #pragma unroll
            for (int mm = 1; mm < 8; ++mm) cm = fmaxf(cm, s[qq][mm]);
            float mn = fmaxf(m_[qq], cm);
            float al = __expf(m_[qq] - mn);
            m_[qq] = mn;
            l_[qq] *= al;
            #pragma unroll
            for (int cc = 0; cc < 32; ++cc) acc[qq][cc] *= al;
            #pragma unroll
            for (int mm = 0; mm < 8; ++mm) {
                float e = __expf(s[qq][mm] - mn);
                s[qq][mm] = e;
                l_[qq] += e;
            }
        }
        // ---- PV phase: V row read once, serves 4 queries ----
        #pragma unroll
        for (int mm = 0; mm < 8; ++mm) {
            const int rl = (mm << 4) | j;
            const float4* vr = (const float4*)&Vsh[rl * 36];
            #pragma unroll
            for (int q4 = 0; q4 < 8; ++q4) {
                const float4 vv = vr[q4];
                #pragma unroll
                for (int qq = 0; qq < 4; ++qq) {
                    const float e = s[qq][mm];
                    acc[qq][4*q4+0] = fmaf(e, vv.x, acc[qq][4*q4+0]);
                    acc[qq][4*q4+1] = fmaf(e, vv.y, acc[qq][4*q4+1]);
                    acc[qq][4*q4+2] = fmaf(e, vv.z, acc[qq][4*q4+2]);
                    acc[qq][4*q4+3] = fmaf(e, vv.w, acc[qq][4*q4+3]);
                }
            }
        }
    }

    // ---- merge across the 16-lane group (online-softmax merge) ----
    #pragma unroll
    for (int qq = 0; qq < 4; ++qq) {
        float M = m_[qq];
        M = fmaxf(M, __shfl_xor(M, 1)); M = fmaxf(M, __shfl_xor(M, 2));
        M = fmaxf(M, __shfl_xor(M, 4)); M = fmaxf(M, __shfl_xor(M, 8));
        float a = __expf(m_[qq] - M);
        float lv = l_[qq] * a;
        lv += __shfl_xor(lv, 1); lv += __shfl_xor(lv, 2);
        lv += __shfl_xor(lv, 4); lv += __shfl_xor(lv, 8);
        l_[qq] = lv;
        #pragma unroll
        for (int cc = 0; cc < 32; ++cc) {
            float v = acc[qq][cc] * a;
            v += __shfl_xor(v, 1); v += __shfl_xor(v, 2);
            v += __shfl_xor(v, 4); v += __shfl_xor(v, 8);
            acc[qq][cc] = v;
        }
    }

    // ---- epilogue: lane j -> query (j&3), out channels [16*(j>>2), +16) ----
    const int qsel = j & 3;
    const float lsel = (qsel == 0) ? l_[0] : (qsel == 1) ? l_[1] : (qsel == 2) ? l_[2] : l_[3];
    const float rL = 1.0f / lsel;
    float gg[32];
    #pragma unroll
    for (int cc = 0; cc < 32; ++cc) {
        float v = (qsel == 0) ? acc[0][cc] : (qsel == 1) ? acc[1][cc]
                : (qsel == 2) ? acc[2][cc] : acc[3][cc];
        gg[cc] = v * rL;
    }

    const int nq = n0 + qsel;
    const int r  = j >> 2;
    const float* xp = x + (size_t)b * (CHn * HWn) + nq;
    float* op = out + (size_t)b * (CHn * HWn) + nq;
    const float4* wpf4 = (const float4*)wpf;
    for (int oo = 0; oo < 16; ++oo) {
        const int o = (r << 4) | oo;
        float sum = pbeta[o];
        #pragma unroll
        for (int c4 = 0; c4 < 8; ++c4) {
            float4 w = wpf4[o * 8 + c4];
            sum += w.x * gg[4*c4] + w.y * gg[4*c4+1] + w.z * gg[4*c4+2] + w.w * gg[4*c4+3];
        }
        op[o * HWn] = xp[o * HWn] + sum;
    }
}

// ------------------------------- launcher ------------------------------------
extern "C" void kernel_launch(void* const* d_in, const int* in_sizes, int n_in,
                              void* d_out, int out_size, void* d_ws, size_t ws_size,
                              hipStream_t stream)
{
    const float* x    = (const float*)d_in[0];
    const float* mem  = (const float*)d_in[1];
    const float* wq   = (const float*)d_in[2];
    const float* bq   = (const float*)d_in[3];
    const float* bnqs = (const float*)d_in[4];
    const float* bnqb = (const float*)d_in[5];
    const float* bnqm = (const float*)d_in[6];
    const float* bnqv = (const float*)d_in[7];
    const float* wk   = (const float*)d_in[8];
    const float* bk   = (const float*)d_in[9];
    const float* bnks = (const float*)d_in[10];
    const float* bnkb = (const float*)d_in[11];
    const float* bnkm = (const float*)d_in[12];
    const float* bnkv = (const float*)d_in[13];
    const float* wv   = (const float*)d_in[14];
    const float* bv   = (const float*)d_in[15];
    const float* bnvs = (const float*)d_in[16];
    const float* bnvb = (const float*)d_in[17];
    const float* bnvm = (const float*)d_in[18];
    const float* bnvv = (const float*)d_in[19];
    const float* wp   = (const float*)d_in[20];
    const float* bp   = (const float*)d_in[21];
    const float* bnps = (const float*)d_in[22];
    const float* bnpb = (const float*)d_in[23];
    const float* bnpm = (const float*)d_in[24];
    const float* bnpv = (const float*)d_in[25];
    const float* gam  = (const float*)d_in[26];

    (void)d_ws; (void)ws_size; (void)in_sizes; (void)n_in; (void)out_size;

    k_proj_kv<<<dim3(256), dim3(192), 0, stream>>>(mem,
        wk, bk, bnks, bnkb, bnkm, bnkv,
        wv, bv, bnvs, bnvb, bnvm, bnvv);
    k_attn3<<<dim3(512), dim3(256), 0, stream>>>(mem, x,
        wq, bq, bnqs, bnqb, bnqm, bnqv,
        wp, bp, bnps, bnpb, bnpm, bnpv, gam,
        (float*)d_out);
}